// Round 5
// baseline (147.290 us; speedup 1.0000x reference)
//
#include <hip/hip_runtime.h>

#define ECE_BINS 20
#define BLOCK    256
#define GRID     2048

// Single fused kernel (last-block-done): per-thread private LDS bin columns
// (bank = tid%32 for any bin -> conflict-free, no atomics; R2 showed LDS
// atomics lane-serialize ~190 cyc), block-reduce, then 20 device-scope global
// atomicAdds per block + counter; last block folds bins -> out.
// Global atomics are device-coherent (cross-XCD safe), unlike plain stores.
__global__ __launch_bounds__(BLOCK) void ece_fused(
    const float4* __restrict__ conf,
    const int4*   __restrict__ corr,
    float* __restrict__ gbins,           // [ECE_BINS], pre-zeroed
    unsigned int* __restrict__ counter,  // pre-zeroed
    float* __restrict__ out,
    int n4, float invN)
{
    __shared__ float s[ECE_BINS * BLOCK];   // 20 KB -> 8 blocks/CU
    __shared__ float s2[ECE_BINS * 8];
    __shared__ bool  s_last;

    const int tid = threadIdx.x;

    #pragma unroll
    for (int b = 0; b < ECE_BINS; ++b) s[b * BLOCK + tid] = 0.0f;
    // no barrier needed: columns are thread-private

    const int idx    = blockIdx.x * BLOCK + tid;
    const int stride = gridDim.x * BLOCK;
    for (int i = idx; i < n4; i += stride) {
        float4 c = conf[i];
        int4   k = corr[i];
        int b0 = min((int)(c.x * 20.0f), ECE_BINS - 1);
        s[b0 * BLOCK + tid] += c.x - (float)k.x;
        int b1 = min((int)(c.y * 20.0f), ECE_BINS - 1);
        s[b1 * BLOCK + tid] += c.y - (float)k.y;
        int b2 = min((int)(c.z * 20.0f), ECE_BINS - 1);
        s[b2 * BLOCK + tid] += c.z - (float)k.z;
        int b3 = min((int)(c.w * 20.0f), ECE_BINS - 1);
        s[b3 * BLOCK + tid] += c.w - (float)k.w;
    }
    __syncthreads();

    // tree-reduce 256 columns per bin
    if (tid < ECE_BINS * 8) {
        int b = tid >> 3, seg = tid & 7;
        float a = 0.0f;
        #pragma unroll
        for (int j = 0; j < 32; ++j) a += s[b * BLOCK + seg * 32 + j];
        s2[tid] = a;
    }
    __syncthreads();

    if (tid < ECE_BINS) {
        float a = 0.0f;
        #pragma unroll
        for (int j = 0; j < 8; ++j) a += s2[tid * 8 + j];
        atomicAdd(&gbins[tid], a);   // device-scope, coherent across XCDs
    }
    __syncthreads();  // vmcnt(0) drain: bin-atomics complete before counter bump

    if (tid == 0) {
        __threadfence();
        unsigned int prev = atomicAdd(counter, 1u);
        s_last = (prev == gridDim.x - 1);
    }
    __syncthreads();

    if (s_last) {
        if (tid < ECE_BINS) {
            // coherent read of the fully-accumulated bin
            float v = atomicAdd(&gbins[tid], 0.0f);
            s2[tid] = fabsf(v);
        }
        __syncthreads();
        if (tid == 0) {
            float sum = 0.0f;
            #pragma unroll
            for (int b = 0; b < ECE_BINS; ++b) sum += s2[b];
            out[0] = sum * invN;
        }
    }
}

extern "C" void kernel_launch(void* const* d_in, const int* in_sizes, int n_in,
                              void* d_out, int out_size, void* d_ws, size_t ws_size,
                              hipStream_t stream) {
    const float4* conf = (const float4*)d_in[0];
    const int4*   corr = (const int4*)d_in[1];
    float* gbins = (float*)d_ws;                       // 20 floats
    unsigned int* counter = (unsigned int*)((char*)d_ws + ECE_BINS * sizeof(float));
    float* out = (float*)d_out;

    int n  = in_sizes[0];
    int n4 = n / 4;  // N = 8388608, divisible by 4

    // zero bins + counter (d_ws is poisoned to 0xAA before every launch)
    hipMemsetAsync(d_ws, 0, ECE_BINS * sizeof(float) + sizeof(unsigned int), stream);

    ece_fused<<<GRID, BLOCK, 0, stream>>>(conf, corr, gbins, counter, out,
                                          n4, 1.0f / (float)n);
}

// Round 6
// 95.342 us; speedup vs baseline: 1.5449x; 1.5449x over previous
//
#include <hip/hip_runtime.h>

#define ECE_BINS 20
#define BLOCK    256
#define GRID     2048   // 8 blocks/CU x 256 CUs: exact residency, no tail

// Pass 1: per-thread PRIVATE LDS bin columns, non-atomic RMW.
// s[b*256+tid]: bank = tid%32 for ANY bin -> conflict-free main loop, no
// atomics (R2: LDS atomics lane-serialize ~190cyc; R5: global-atomic storm
// costs ~55us). Epilogue reduce uses ROTATED indexing — the naive stride-32
// row-sum is a 64-way bank conflict (R5 counter: 1.15M conflict cycles).
// LDS is exactly 20480 B (stage-2 scratch overlays s) -> 8 blocks/CU.
__global__ __launch_bounds__(BLOCK) void ece_pass1(
    const float4* __restrict__ conf,
    const int4*   __restrict__ corr,
    float* __restrict__ partials,   // [GRID][ECE_BINS]
    int n4)
{
    __shared__ float s[ECE_BINS * BLOCK];   // 20480 B exactly

    const int tid = threadIdx.x;

    #pragma unroll
    for (int b = 0; b < ECE_BINS; ++b) s[b * BLOCK + tid] = 0.0f;
    // no barrier: columns are thread-private

    const int idx    = blockIdx.x * BLOCK + tid;
    const int stride = GRID * BLOCK;
    for (int i = idx; i < n4; i += stride) {
        float4 c = conf[i];
        int4   k = corr[i];
        int b0 = min((int)(c.x * 20.0f), ECE_BINS - 1);
        s[b0 * BLOCK + tid] += c.x - (float)k.x;
        int b1 = min((int)(c.y * 20.0f), ECE_BINS - 1);
        s[b1 * BLOCK + tid] += c.y - (float)k.y;
        int b2 = min((int)(c.z * 20.0f), ECE_BINS - 1);
        s[b2 * BLOCK + tid] += c.z - (float)k.z;
        int b3 = min((int)(c.w * 20.0f), ECE_BINS - 1);
        s[b3 * BLOCK + tid] += c.w - (float)k.w;
    }
    __syncthreads();

    // stage 1: 160 threads sum 32 columns each, rotated -> all 32 banks busy
    float a = 0.0f;
    if (tid < ECE_BINS * 8) {
        const int base = (tid >> 3) * BLOCK + (tid & 7) * 32;
        #pragma unroll
        for (int j = 0; j < 32; ++j) {
            int jj = (j + tid) & 31;
            a += s[base + jj];
        }
    }
    __syncthreads();
    if (tid < ECE_BINS * 8) s[tid] = a;   // overlay scratch, barrier-separated
    __syncthreads();

    // stage 2: 20 threads sum 8 partials, rotated
    if (tid < ECE_BINS) {
        float t = 0.0f;
        #pragma unroll
        for (int j = 0; j < 8; ++j) {
            int jj = (j + tid) & 7;
            t += s[tid * 8 + jj];
        }
        partials[blockIdx.x * ECE_BINS + tid] = t;
    }
}

// Pass 2: reduce [nb][20] partials -> out = (1/N) * sum_b |bin_b|
__global__ __launch_bounds__(256) void ece_pass2(
    const float4* __restrict__ partials,  // rows of 20 floats = 5 x float4
    float* __restrict__ out,
    int nb, float invN)
{
    __shared__ float s[ECE_BINS * 256];

    const int tid = threadIdx.x;
    float acc[ECE_BINS];
    #pragma unroll
    for (int b = 0; b < ECE_BINS; ++b) acc[b] = 0.0f;

    for (int row = tid; row < nb; row += 256) {
        const float4* r = partials + row * 5;
        #pragma unroll
        for (int q = 0; q < 5; ++q) {
            float4 v = r[q];
            acc[q * 4 + 0] += v.x;
            acc[q * 4 + 1] += v.y;
            acc[q * 4 + 2] += v.z;
            acc[q * 4 + 3] += v.w;
        }
    }
    #pragma unroll
    for (int b = 0; b < ECE_BINS; ++b) s[b * 256 + tid] = acc[b];
    __syncthreads();

    float a = 0.0f;
    if (tid < ECE_BINS * 8) {
        const int base = (tid >> 3) * 256 + (tid & 7) * 32;
        #pragma unroll
        for (int j = 0; j < 32; ++j) {
            int jj = (j + tid) & 31;
            a += s[base + jj];
        }
    }
    __syncthreads();
    if (tid < ECE_BINS * 8) s[tid] = a;
    __syncthreads();

    if (tid < ECE_BINS) {
        float t = 0.0f;
        #pragma unroll
        for (int j = 0; j < 8; ++j) {
            int jj = (j + tid) & 7;
            t += s[tid * 8 + jj];
        }
        s[256 + tid] = fabsf(t);   // scratch slot, past stage-1 region
    }
    __syncthreads();
    if (tid == 0) {
        float sum = 0.0f;
        #pragma unroll
        for (int b = 0; b < ECE_BINS; ++b) sum += s[256 + b];
        out[0] = sum * invN;
    }
}

extern "C" void kernel_launch(void* const* d_in, const int* in_sizes, int n_in,
                              void* d_out, int out_size, void* d_ws, size_t ws_size,
                              hipStream_t stream) {
    const float4* conf = (const float4*)d_in[0];
    const int4*   corr = (const int4*)d_in[1];
    float* partials = (float*)d_ws;
    float* out      = (float*)d_out;

    int n  = in_sizes[0];
    int n4 = n / 4;  // N = 8388608, divisible by 4

    ece_pass1<<<GRID, BLOCK, 0, stream>>>(conf, corr, partials, n4);
    ece_pass2<<<1, 256, 0, stream>>>((const float4*)partials, out, GRID, 1.0f / (float)n);
}